// Round 8
// baseline (102.084 us; speedup 1.0000x reference)
//
#include <hip/hip_runtime.h>
#include <math.h>

#define NNODE 120000
#define DDIM  128
#define SS    100
#define NNEGS 50
#define ROWS_A 1600    // anchor/positive rows per type: slice(4) x idset(4) x 100
#define ROWS_N 20000   // cross-neg rows per type: vl(4) x s(100) x n(50)
#define TOTAL_ROWS 43200
#define BLK_ROWS 128
#define GRID_ROWS 43264                      // 338 blocks x 128 (pad clamps to last row)
#define ZPAD_ROWS 43264
#define WFRAG_SHORTS 16384                   // per layer: kc(4) x ct(8) x lane(64) x 8
#define INV_TEMP 2.0f

typedef unsigned short ushort_t;
typedef __attribute__((ext_vector_type(8))) short bf16x8;
typedef __attribute__((ext_vector_type(8))) unsigned short u16x8;
typedef __attribute__((ext_vector_type(4))) float f32x4;

__device__ __forceinline__ ushort_t f2b(float f) {
  unsigned u = __builtin_bit_cast(unsigned, f);
  u += 0x7fffu + ((u >> 16) & 1u);           // RNE
  return (ushort_t)(u >> 16);
}
__device__ __forceinline__ float b2f(ushort_t h) {
  return __builtin_bit_cast(float, (unsigned)h << 16);
}
__device__ __forceinline__ bool idx_is64(const void* p) {
  const unsigned* q = (const unsigned*)p;
  return (q[1] | q[3] | q[5] | q[7]) == 0u;
}
__device__ __forceinline__ int ld_idx(const void* p, int i, bool is64) {
  return is64 ? (int)((const long long*)p)[i] : ((const int*)p)[i];
}

// zrows layout (bf16 rows of 128):
//   [0,1600) A_p | [1600,3200) A_c | [3200,23200) N_pc | [23200,43200) N_cp | pad
__device__ __forceinline__ const float* row_src(
    int rid, bool is64,
    const float* emb_p, const float* emb_c,
    const void* idx_p, const void* idx_c,
    const void* nidx_p, const void* nidx_c)
{
  if (rid < 2 * ROWS_A) {
    const int typ = rid / ROWS_A;
    const int rr  = rid - typ * ROWS_A;
    const int slice = rr / 400;
    const int rem   = rr - slice * 400;          // idset*100 + s
    const int node  = ld_idx(typ ? idx_c : idx_p, rem, is64);
    return (typ ? emb_c : emb_p) + ((size_t)slice * NNODE + node) * DDIM;
  } else {
    const int r2  = rid - 2 * ROWS_A;
    const int typ = r2 / ROWS_N;
    const int rr  = r2 - typ * ROWS_N;
    const int slice = rr / (SS * NNEGS);
    const int rem   = rr - slice * (SS * NNEGS);
    const int node  = ld_idx(typ ? nidx_c : nidx_p, slice * (SS * NNEGS) + rem, is64);
    return (typ ? emb_p : emb_c) + ((size_t)slice * NNODE + node) * DDIM;
  }
}

// W -> B-fragment order (bf16): frag[layer][kc][ct][lane][e] =
//   W[kc*32 + 8*(lane>>4) + e][ct*16 + (lane&15)]
__global__ __launch_bounds__(64)
void wfrag_kernel(const float* __restrict__ W1, const float* __restrict__ W2,
                  ushort_t* __restrict__ wfrag, float* __restrict__ out)
{
  if (blockIdx.x == 0 && threadIdx.x == 0) out[0] = 0.f;   // fold memset node
  const int b = blockIdx.x;                 // 64 = layer(2) x kc(4) x ct(8)
  const int layer = b >> 5, kc = (b >> 3) & 3, ct = b & 7;
  const int l = threadIdx.x;
  const float* W = layer ? W2 : W1;
  ushort_t* dst = wfrag + layer * WFRAG_SHORTS + (size_t)((kc * 8 + ct) * 64 + l) * 8;
  const int col   = ct * 16 + (l & 15);
  const int krow0 = kc * 32 + ((l >> 4) << 3);
  #pragma unroll
  for (int e = 0; e < 8; ++e)
    dst[e] = f2b(W[(size_t)(krow0 + e) * DDIM + col]);
}

__global__ __launch_bounds__(512)
void proj_kernel(const float* __restrict__ emb_p, const float* __restrict__ emb_c,
                 const float* __restrict__ b1v, const float* __restrict__ b2v,
                 const void* __restrict__ idx_p, const void* __restrict__ idx_c,
                 const void* __restrict__ nidx_p, const void* __restrict__ nidx_c,
                 const ushort_t* __restrict__ wfrag,
                 ushort_t* __restrict__ zout)
{
  __shared__ __align__(16) ushort_t wlds[WFRAG_SHORTS];       // 32 KB, one layer at a time
  __shared__ __align__(16) ushort_t hlds[BLK_ROWS * DDIM];    // 32 KB, wave-private 16-row slabs
  const int t = threadIdx.x, w = t >> 6, l = t & 63;
  const int g = l >> 4, li = l & 15;
  const bool is64 = idx_is64(idx_p);
  const int base = blockIdx.x * BLK_ROWS;
  const int r0 = w * 16;
  char* hb = (char*)hlds;

  // ---- issue this lane's row gather FIRST (HBM latency hides under staging) ----
  int rid = base + r0 + li;
  if (rid > TOTAL_ROWS - 1) rid = TOTAL_ROWS - 1;
  const float* src = row_src(rid, is64, emb_p, emb_c, idx_p, idx_c, nidx_p, nidx_c);
  float4 xr[8];
  #pragma unroll
  for (int kc = 0; kc < 4; ++kc) {
    xr[2 * kc]     = *(const float4*)(src + kc * 32 + g * 8);
    xr[2 * kc + 1] = *(const float4*)(src + kc * 32 + g * 8 + 4);
  }
  // ---- stage W1 frags (32 KB from L2) ----
  {
    const uint4* s4 = (const uint4*)wfrag;
    uint4* d4 = (uint4*)wlds;
    #pragma unroll
    for (int i = 0; i < 4; ++i) d4[t + 512 * i] = s4[t + 512 * i];
  }
  // convert gathered row to A fragments
  bf16x8 afrag[4];
  #pragma unroll
  for (int kc = 0; kc < 4; ++kc) {
    const float4 xa = xr[2 * kc], xb = xr[2 * kc + 1];
    bf16x8 af;
    af[0]=(short)f2b(xa.x); af[1]=(short)f2b(xa.y); af[2]=(short)f2b(xa.z); af[3]=(short)f2b(xa.w);
    af[4]=(short)f2b(xb.x); af[5]=(short)f2b(xb.y); af[6]=(short)f2b(xb.z); af[7]=(short)f2b(xb.w);
    afrag[kc] = af;
  }
  __syncthreads();                                   // W1 visible

  f32x4 acc[8];
  // ---- layer 1: H = relu(X @ W1 + b1) ----
  #pragma unroll
  for (int ct = 0; ct < 8; ++ct) {
    const float bv = b1v[ct * 16 + li];
    acc[ct] = (f32x4){bv, bv, bv, bv};
  }
  #pragma unroll
  for (int kc = 0; kc < 4; ++kc)
    #pragma unroll
    for (int ct = 0; ct < 8; ++ct)
      acc[ct] = __builtin_amdgcn_mfma_f32_16x16x32_bf16(
          afrag[kc], *(const bf16x8*)&wlds[((kc * 8 + ct) * 64 + l) * 8], acc[ct], 0, 0, 0);

  // relu -> hlds (XOR-swizzled rows; slab is wave-private, DS in-order per wave)
  #pragma unroll
  for (int ct = 0; ct < 8; ++ct)
    #pragma unroll
    for (int rg = 0; rg < 4; ++rg) {
      const int row = r0 + 4 * g + rg;
      const int byte = row * 256 + (ct * 16 + li) * 2;
      *(ushort_t*)(hb + (byte ^ ((row & 7) << 4))) = f2b(fmaxf(acc[ct][rg], 0.f));
    }
  __syncthreads();                                   // all waves done reading W1
  // ---- stage W2 frags over W1 ----
  {
    const uint4* s4 = (const uint4*)(wfrag + WFRAG_SHORTS);
    uint4* d4 = (uint4*)wlds;
    #pragma unroll
    for (int i = 0; i < 4; ++i) d4[t + 512 * i] = s4[t + 512 * i];
  }
  __syncthreads();                                   // W2 visible

  // ---- layer 2: Z = H @ W2 + b2 ----
  #pragma unroll
  for (int ct = 0; ct < 8; ++ct) {
    const float bv = b2v[ct * 16 + li];
    acc[ct] = (f32x4){bv, bv, bv, bv};
  }
  {
    const int row = r0 + li;
    #pragma unroll
    for (int kc = 0; kc < 4; ++kc) {
      const int byte = row * 256 + kc * 64 + g * 16;
      const bf16x8 hf = *(const bf16x8*)(hb + (byte ^ ((row & 7) << 4)));
      #pragma unroll
      for (int ct = 0; ct < 8; ++ct)
        acc[ct] = __builtin_amdgcn_mfma_f32_16x16x32_bf16(
            hf, *(const bf16x8*)&wlds[((kc * 8 + ct) * 64 + l) * 8], acc[ct], 0, 0, 0);
    }
  }
  // ---- L2 norm (rows live across the 16-lane group) ----
  float sc[4];
  #pragma unroll
  for (int rg = 0; rg < 4; ++rg) {
    float ssq = 0.f;
    #pragma unroll
    for (int ct = 0; ct < 8; ++ct) ssq += acc[ct][rg] * acc[ct][rg];
    ssq += __shfl_xor(ssq, 1);
    ssq += __shfl_xor(ssq, 2);
    ssq += __shfl_xor(ssq, 4);
    ssq += __shfl_xor(ssq, 8);
    sc[rg] = 1.f / fmaxf(sqrtf(ssq), 1e-12f);
  }
  // normalized z (bf16) -> own slab, linear layout (own H reads already done; in-order DS)
  #pragma unroll
  for (int ct = 0; ct < 8; ++ct)
    #pragma unroll
    for (int rg = 0; rg < 4; ++rg)
      hlds[(r0 + 4 * g + rg) * DDIM + ct * 16 + li] = f2b(acc[ct][rg] * sc[rg]);
  // coalesced 4 KB copy-out of own slab (no barrier: wave-private)
  {
    const uint4* s4 = (const uint4*)&hlds[r0 * DDIM];
    uint4* d4 = (uint4*)(zout + (size_t)(base + r0) * DDIM);
    #pragma unroll
    for (int i = 0; i < 4; ++i) d4[l + 64 * i] = s4[l + 64 * i];
  }
}

// one target per lane: lane computes its full 128-dot, single reduce per wave
__global__ __launch_bounds__(192)
void loss_kernel(const ushort_t* __restrict__ zb, float* __restrict__ out)
{
  __shared__ __align__(16) float zf[DDIM];
  __shared__ float sp[3], sn[3];
  const int bid = blockIdx.x;            // type(2) x vl(4) x s(100)
  const int typ = bid / 400;
  const int rem = bid - typ * 400;
  const int vl  = rem / SS;
  const int s   = rem - vl * SS;
  const ushort_t* A  = zb + (size_t)(typ ? ROWS_A : 0) * DDIM;
  const ushort_t* Nb = zb + (size_t)(2 * ROWS_A + (typ ? ROWS_N : 0)) * DDIM;
  const ushort_t* zs = A + (size_t)((vl * 4 + vl) * SS + s) * DDIM;
  const int t = threadIdx.x, lane = t & 63, w = t >> 6;

  if (t < DDIM) zf[t] = b2f(zs[t]);
  __syncthreads();

  float e = 0.f;
  if (t < 152) {
    const ushort_t* tp;
    if (t < 3) {                                     // positives: other 3 slices
      const int k = t + (t >= vl ? 1 : 0);
      tp = A + (size_t)((k * 4 + vl) * SS + s) * DDIM;
    } else if (t < 102) {                            // within-negs, skip self
      int t2 = t - 3;
      if (t2 >= s) ++t2;
      tp = A + (size_t)((vl * 4 + vl) * SS + t2) * DDIM;
    } else {                                         // cross-negs
      tp = Nb + (size_t)((vl * SS + s) * NNEGS + (t - 102)) * DDIM;
    }
    float d0 = 0.f, d1 = 0.f, d2 = 0.f, d3 = 0.f;
    #pragma unroll
    for (int c = 0; c < 16; ++c) {
      const u16x8 tv = *(const u16x8*)(tp + c * 8);
      const float4 za = *(const float4*)&zf[c * 8];
      const float4 zc = *(const float4*)&zf[c * 8 + 4];
      d0 = fmaf(b2f(tv[0]), za.x, d0);
      d1 = fmaf(b2f(tv[1]), za.y, d1);
      d2 = fmaf(b2f(tv[2]), za.z, d2);
      d3 = fmaf(b2f(tv[3]), za.w, d3);
      d0 = fmaf(b2f(tv[4]), zc.x, d0);
      d1 = fmaf(b2f(tv[5]), zc.y, d1);
      d2 = fmaf(b2f(tv[6]), zc.z, d2);
      d3 = fmaf(b2f(tv[7]), zc.w, d3);
    }
    e = __expf(((d0 + d1) + (d2 + d3)) * INV_TEMP);
  }
  float pe = (t < 3) ? e : 0.f;
  float ne = (t < 3) ? 0.f : e;
  #pragma unroll
  for (int m = 1; m < 64; m <<= 1) {
    pe += __shfl_xor(pe, m);
    ne += __shfl_xor(ne, m);
  }
  if (lane == 0) { sp[w] = pe; sn[w] = ne; }
  __syncthreads();
  if (t == 0) {
    const float P  = sp[0] + sp[1] + sp[2];
    const float Ng = sn[0] + sn[1] + sn[2];
    atomicAdd(out, -logf(P / (P + Ng)) * (1.0f / 800.0f));
  }
}

extern "C" void kernel_launch(void* const* d_in, const int* in_sizes, int n_in,
                              void* d_out, int out_size, void* d_ws, size_t ws_size,
                              hipStream_t stream) {
  const float* emb_p = (const float*)d_in[0];
  const float* emb_c = (const float*)d_in[1];
  const float* W1    = (const float*)d_in[2];
  const float* b1    = (const float*)d_in[3];
  const float* W2    = (const float*)d_in[4];
  const float* b2    = (const float*)d_in[5];
  const void*  idx_p  = d_in[6];
  const void*  idx_c  = d_in[7];
  const void*  nidx_p = d_in[8];
  const void*  nidx_c = d_in[9];
  float* out = (float*)d_out;

  // ws layout: 3 z-buffers + wfrag + dummy loss outputs (DIAGNOSTIC ROUND:
  // proj x3 and loss x3 to attribute dur = floor + overheads + 3P + 3L)
  ushort_t* z1 = (ushort_t*)d_ws;
  ushort_t* z2 = z1 + (size_t)ZPAD_ROWS * DDIM;
  ushort_t* z3 = z2 + (size_t)ZPAD_ROWS * DDIM;
  ushort_t* wfrag = z3 + (size_t)ZPAD_ROWS * DDIM;
  float* dummy = (float*)(wfrag + 2 * WFRAG_SHORTS);

  wfrag_kernel<<<64, 64, 0, stream>>>(W1, W2, wfrag, out);
  proj_kernel<<<GRID_ROWS / BLK_ROWS, 512, 0, stream>>>(
      emb_p, emb_c, b1, b2, idx_p, idx_c, nidx_p, nidx_c, wfrag, z1);
  proj_kernel<<<GRID_ROWS / BLK_ROWS, 512, 0, stream>>>(
      emb_p, emb_c, b1, b2, idx_p, idx_c, nidx_p, nidx_c, wfrag, z2);
  proj_kernel<<<GRID_ROWS / BLK_ROWS, 512, 0, stream>>>(
      emb_p, emb_c, b1, b2, idx_p, idx_c, nidx_p, nidx_c, wfrag, z3);
  loss_kernel<<<800, 192, 0, stream>>>(z1, out);
  loss_kernel<<<800, 192, 0, stream>>>(z2, dummy);
  loss_kernel<<<800, 192, 0, stream>>>(z3, dummy + 16);
}

// Round 9
// 37.909 us; speedup vs baseline: 2.6929x; 2.6929x over previous
//
#include <hip/hip_runtime.h>
#include <math.h>

#define NNODE 120000
#define DDIM  128
#define SS    100
#define NNEGS 50
#define ROWS_A 1600    // anchor/positive rows per type: slice(4) x idset(4) x 100
#define ROWS_N 20000   // cross-neg rows per type: vl(4) x s(100) x n(50)
#define TOTAL_ROWS 43200
#define BLK_ROWS 128
#define GRID_ROWS 43264                      // 338 blocks x 128 (pad clamps to last row)
#define INV_TEMP 2.0f

typedef unsigned short ushort_t;
typedef __attribute__((ext_vector_type(8))) short bf16x8;
typedef __attribute__((ext_vector_type(8))) unsigned short u16x8;
typedef __attribute__((ext_vector_type(4))) float f32x4;

__device__ __forceinline__ ushort_t f2b(float f) {
  unsigned u = __builtin_bit_cast(unsigned, f);
  u += 0x7fffu + ((u >> 16) & 1u);           // RNE
  return (ushort_t)(u >> 16);
}
__device__ __forceinline__ float b2f(ushort_t h) {
  return __builtin_bit_cast(float, (unsigned)h << 16);
}
__device__ __forceinline__ bool idx_is64(const void* p) {
  const unsigned* q = (const unsigned*)p;
  return (q[1] | q[3] | q[5] | q[7]) == 0u;
}
__device__ __forceinline__ int ld_idx(const void* p, int i, bool is64) {
  return is64 ? (int)((const long long*)p)[i] : ((const int*)p)[i];
}

// zrows layout (bf16 rows of 128):
//   [0,1600) A_p | [1600,3200) A_c | [3200,23200) N_pc | [23200,43200) N_cp | pad
__device__ __forceinline__ const float* row_src(
    int rid, bool is64,
    const float* emb_p, const float* emb_c,
    const void* idx_p, const void* idx_c,
    const void* nidx_p, const void* nidx_c)
{
  if (rid < 2 * ROWS_A) {
    const int typ = rid / ROWS_A;
    const int rr  = rid - typ * ROWS_A;
    const int slice = rr / 400;
    const int rem   = rr - slice * 400;          // idset*100 + s
    const int node  = ld_idx(typ ? idx_c : idx_p, rem, is64);
    return (typ ? emb_c : emb_p) + ((size_t)slice * NNODE + node) * DDIM;
  } else {
    const int r2  = rid - 2 * ROWS_A;
    const int typ = r2 / ROWS_N;
    const int rr  = r2 - typ * ROWS_N;
    const int slice = rr / (SS * NNEGS);
    const int rem   = rr - slice * (SS * NNEGS);
    const int node  = ld_idx(typ ? nidx_c : nidx_p, slice * (SS * NNEGS) + rem, is64);
    return (typ ? emb_p : emb_c) + ((size_t)slice * NNODE + node) * DDIM;
  }
}

// Conflict-free in-block W-fragment build:
// slot s = p*512+t covers (kcct = s>>6, lane = s&63); thread reads 8 column-strided
// f32 (16-lane x 64B coalesced, L2-hot) and writes ONE contiguous 16B LDS chunk.
// Layout matches verified wfrag: wl[((kc*8+ct)*64+lane)*8+e] =
//   f2b(W[kc*32 + 8*(lane>>4) + e][ct*16 + (lane&15)])
__device__ __forceinline__ void build_wfrag_cf(const float* __restrict__ W,
                                               ushort_t* __restrict__ wl, int t)
{
  #pragma unroll
  for (int p = 0; p < 4; ++p) {
    const int s = p * 512 + t;
    const int lane = s & 63, kcct = s >> 6;
    const int kc = kcct >> 3, ct = kcct & 7;
    const int col  = ct * 16 + (lane & 15);
    const int row0 = kc * 32 + ((lane >> 4) << 3);
    const float* wp = W + (size_t)row0 * DDIM + col;
    u16x8 v;
    #pragma unroll
    for (int e = 0; e < 8; ++e) v[e] = f2b(wp[(size_t)e * DDIM]);
    *(u16x8*)&wl[(size_t)s * 8] = v;     // single ds_write_b128, linear across banks
  }
}

__global__ __launch_bounds__(512, 4)
void proj_kernel(const float* __restrict__ emb_p, const float* __restrict__ emb_c,
                 const float* __restrict__ W1, const float* __restrict__ b1v,
                 const float* __restrict__ W2, const float* __restrict__ b2v,
                 const void* __restrict__ idx_p, const void* __restrict__ idx_c,
                 const void* __restrict__ nidx_p, const void* __restrict__ nidx_c,
                 ushort_t* __restrict__ zout, float* __restrict__ out)
{
  __shared__ __align__(16) ushort_t wlds[16384];              // 32 KB, one layer at a time
  __shared__ __align__(16) ushort_t hlds[BLK_ROWS * DDIM];    // 32 KB, wave-private 16-row slabs
  const int t = threadIdx.x, w = t >> 6, l = t & 63;
  const int g = l >> 4, li = l & 15;
  const bool is64 = idx_is64(idx_p);
  const int base = blockIdx.x * BLK_ROWS;
  const int r0 = w * 16;
  char* hb = (char*)hlds;

  if (blockIdx.x == 0 && t == 0) out[0] = 0.f;   // loss launches after proj completes

  // ---- issue this lane's row gather FIRST (HBM latency hides under W1 build) ----
  int rid = base + r0 + li;
  if (rid > TOTAL_ROWS - 1) rid = TOTAL_ROWS - 1;
  const float* src = row_src(rid, is64, emb_p, emb_c, idx_p, idx_c, nidx_p, nidx_c);
  float4 xr[8];
  #pragma unroll
  for (int kc = 0; kc < 4; ++kc) {
    xr[2 * kc]     = *(const float4*)(src + kc * 32 + g * 8);
    xr[2 * kc + 1] = *(const float4*)(src + kc * 32 + g * 8 + 4);
  }
  // ---- build W1 frags in LDS (conflict-free; overlaps gather latency) ----
  build_wfrag_cf(W1, wlds, t);
  // convert gathered row to A fragments
  bf16x8 afrag[4];
  #pragma unroll
  for (int kc = 0; kc < 4; ++kc) {
    const float4 xa = xr[2 * kc], xb = xr[2 * kc + 1];
    bf16x8 af;
    af[0]=(short)f2b(xa.x); af[1]=(short)f2b(xa.y); af[2]=(short)f2b(xa.z); af[3]=(short)f2b(xa.w);
    af[4]=(short)f2b(xb.x); af[5]=(short)f2b(xb.y); af[6]=(short)f2b(xb.z); af[7]=(short)f2b(xb.w);
    afrag[kc] = af;
  }
  __syncthreads();                                   // W1 visible

  f32x4 acc[8];
  // ---- layer 1: H = relu(X @ W1 + b1) ----
  #pragma unroll
  for (int ct = 0; ct < 8; ++ct) {
    const float bv = b1v[ct * 16 + li];
    acc[ct] = (f32x4){bv, bv, bv, bv};
  }
  #pragma unroll
  for (int kc = 0; kc < 4; ++kc)
    #pragma unroll
    for (int ct = 0; ct < 8; ++ct)
      acc[ct] = __builtin_amdgcn_mfma_f32_16x16x32_bf16(
          afrag[kc], *(const bf16x8*)&wlds[((kc * 8 + ct) * 64 + l) * 8], acc[ct], 0, 0, 0);

  // relu -> hlds (XOR-swizzled rows; slab is wave-private, DS in-order per wave)
  #pragma unroll
  for (int ct = 0; ct < 8; ++ct)
    #pragma unroll
    for (int rg = 0; rg < 4; ++rg) {
      const int row = r0 + 4 * g + rg;
      const int byte = row * 256 + (ct * 16 + li) * 2;
      *(ushort_t*)(hb + (byte ^ ((row & 7) << 4))) = f2b(fmaxf(acc[ct][rg], 0.f));
    }
  __syncthreads();                                   // all waves done reading W1
  // ---- build W2 frags over W1 ----
  build_wfrag_cf(W2, wlds, t);
  __syncthreads();                                   // W2 visible

  // ---- layer 2: Z = H @ W2 + b2 ----
  #pragma unroll
  for (int ct = 0; ct < 8; ++ct) {
    const float bv = b2v[ct * 16 + li];
    acc[ct] = (f32x4){bv, bv, bv, bv};
  }
  {
    const int row = r0 + li;
    #pragma unroll
    for (int kc = 0; kc < 4; ++kc) {
      const int byte = row * 256 + kc * 64 + g * 16;
      const bf16x8 hf = *(const bf16x8*)(hb + (byte ^ ((row & 7) << 4)));
      #pragma unroll
      for (int ct = 0; ct < 8; ++ct)
        acc[ct] = __builtin_amdgcn_mfma_f32_16x16x32_bf16(
            hf, *(const bf16x8*)&wlds[((kc * 8 + ct) * 64 + l) * 8], acc[ct], 0, 0, 0);
    }
  }
  // ---- L2 norm (rows live across the 16-lane group) ----
  float sc[4];
  #pragma unroll
  for (int rg = 0; rg < 4; ++rg) {
    float ssq = 0.f;
    #pragma unroll
    for (int ct = 0; ct < 8; ++ct) ssq += acc[ct][rg] * acc[ct][rg];
    ssq += __shfl_xor(ssq, 1);
    ssq += __shfl_xor(ssq, 2);
    ssq += __shfl_xor(ssq, 4);
    ssq += __shfl_xor(ssq, 8);
    sc[rg] = 1.f / fmaxf(sqrtf(ssq), 1e-12f);
  }
  // normalized z (bf16) -> own slab, linear layout (own H reads already done; in-order DS)
  #pragma unroll
  for (int ct = 0; ct < 8; ++ct)
    #pragma unroll
    for (int rg = 0; rg < 4; ++rg)
      hlds[(r0 + 4 * g + rg) * DDIM + ct * 16 + li] = f2b(acc[ct][rg] * sc[rg]);
  // coalesced 4 KB copy-out of own slab (no barrier: wave-private)
  {
    const uint4* s4 = (const uint4*)&hlds[r0 * DDIM];
    uint4* d4 = (uint4*)(zout + (size_t)(base + r0) * DDIM);
    #pragma unroll
    for (int i = 0; i < 4; ++i) d4[l + 64 * i] = s4[l + 64 * i];
  }
}

// one target per lane: lane computes its full 128-dot, single reduce per wave
__global__ __launch_bounds__(192)
void loss_kernel(const ushort_t* __restrict__ zb, float* __restrict__ out)
{
  __shared__ __align__(16) float zf[DDIM];
  __shared__ float sp[3], sn[3];
  const int bid = blockIdx.x;            // type(2) x vl(4) x s(100)
  const int typ = bid / 400;
  const int rem = bid - typ * 400;
  const int vl  = rem / SS;
  const int s   = rem - vl * SS;
  const ushort_t* A  = zb + (size_t)(typ ? ROWS_A : 0) * DDIM;
  const ushort_t* Nb = zb + (size_t)(2 * ROWS_A + (typ ? ROWS_N : 0)) * DDIM;
  const ushort_t* zs = A + (size_t)((vl * 4 + vl) * SS + s) * DDIM;
  const int t = threadIdx.x, lane = t & 63, w = t >> 6;

  if (t < DDIM) zf[t] = b2f(zs[t]);
  __syncthreads();

  float e = 0.f;
  if (t < 152) {
    const ushort_t* tp;
    if (t < 3) {                                     // positives: other 3 slices
      const int k = t + (t >= vl ? 1 : 0);
      tp = A + (size_t)((k * 4 + vl) * SS + s) * DDIM;
    } else if (t < 102) {                            // within-negs, skip self
      int t2 = t - 3;
      if (t2 >= s) ++t2;
      tp = A + (size_t)((vl * 4 + vl) * SS + t2) * DDIM;
    } else {                                         // cross-negs
      tp = Nb + (size_t)((vl * SS + s) * NNEGS + (t - 102)) * DDIM;
    }
    float d0 = 0.f, d1 = 0.f, d2 = 0.f, d3 = 0.f;
    #pragma unroll
    for (int c = 0; c < 16; ++c) {
      const u16x8 tv = *(const u16x8*)(tp + c * 8);
      const float4 za = *(const float4*)&zf[c * 8];
      const float4 zc = *(const float4*)&zf[c * 8 + 4];
      d0 = fmaf(b2f(tv[0]), za.x, d0);
      d1 = fmaf(b2f(tv[1]), za.y, d1);
      d2 = fmaf(b2f(tv[2]), za.z, d2);
      d3 = fmaf(b2f(tv[3]), za.w, d3);
      d0 = fmaf(b2f(tv[4]), zc.x, d0);
      d1 = fmaf(b2f(tv[5]), zc.y, d1);
      d2 = fmaf(b2f(tv[6]), zc.z, d2);
      d3 = fmaf(b2f(tv[7]), zc.w, d3);
    }
    e = __expf(((d0 + d1) + (d2 + d3)) * INV_TEMP);
  }
  float pe = (t < 3) ? e : 0.f;
  float ne = (t < 3) ? 0.f : e;
  #pragma unroll
  for (int m = 1; m < 64; m <<= 1) {
    pe += __shfl_xor(pe, m);
    ne += __shfl_xor(ne, m);
  }
  if (lane == 0) { sp[w] = pe; sn[w] = ne; }
  __syncthreads();
  if (t == 0) {
    const float P  = sp[0] + sp[1] + sp[2];
    const float Ng = sn[0] + sn[1] + sn[2];
    atomicAdd(out, -logf(P / (P + Ng)) * (1.0f / 800.0f));
  }
}

extern "C" void kernel_launch(void* const* d_in, const int* in_sizes, int n_in,
                              void* d_out, int out_size, void* d_ws, size_t ws_size,
                              hipStream_t stream) {
  const float* emb_p = (const float*)d_in[0];
  const float* emb_c = (const float*)d_in[1];
  const float* W1    = (const float*)d_in[2];
  const float* b1    = (const float*)d_in[3];
  const float* W2    = (const float*)d_in[4];
  const float* b2    = (const float*)d_in[5];
  const void*  idx_p  = d_in[6];
  const void*  idx_c  = d_in[7];
  const void*  nidx_p = d_in[8];
  const void*  nidx_c = d_in[9];
  float* out = (float*)d_out;
  ushort_t* zrows = (ushort_t*)d_ws;

  proj_kernel<<<GRID_ROWS / BLK_ROWS, 512, 0, stream>>>(
      emb_p, emb_c, W1, b1, W2, b2, idx_p, idx_c, nidx_p, nidx_c, zrows, out);
  loss_kernel<<<800, 192, 0, stream>>>(zrows, out);
}